// Round 13
// baseline (172.045 us; speedup 1.0000x reference)
//
#include <hip/hip_runtime.h>
#include <math.h>

#define FEAT 128
#define EMBED 64
#define CLS 40

#define GRP 512          // nodes per bucket (pow2)
#define GSH 9            // log2(GRP)
#define STRIDE 12288     // pairs-buffer slots per bucket (mean fill ~8163)
#define T1 2048          // edges per phase-1 tile

typedef __attribute__((ext_vector_type(8))) short s8v;    // 8 bf16
typedef __attribute__((ext_vector_type(4))) float f32x4;  // MFMA acc

static __device__ __forceinline__ float bf2f(unsigned short u) {
    union { unsigned int i; float f; } c; c.i = ((unsigned int)u) << 16; return c.f;
}
static __device__ __forceinline__ unsigned short f2bf(float f) {
    union { float f; unsigned int i; } c; c.f = f;
    unsigned int x = c.i;
    x += 0x7fffu + ((x >> 16) & 1u);   // RNE
    return (unsigned short)(x >> 16);
}

// ---------------- cursor init ----------------

__global__ void k_initcur(int* __restrict__ cursor, int B) {
    int t = blockIdx.x * blockDim.x + threadIdx.x;
    if (t < B) cursor[t] = t * STRIDE;
}

// ---------------- phase 1: LDS counting-sort tiles into bucketed packed pairs ----------------
// packed pair: bits 25..17 = dst&511 (bucket-local), bits 16..0 = src  (N < 2^17)

__global__ __launch_bounds__(256) void k_p1(const int* __restrict__ ei,
                                            unsigned int* __restrict__ pairs,
                                            int* __restrict__ cursor, int E, int B) {
    __shared__ unsigned long long pl[T1];            // 16 KB (needs full dst for bucket)
    __shared__ int hist[256], base[256], gbase[256], lcnt[256], scanbuf[256];
    int tid = threadIdx.x;
    int tile0 = blockIdx.x * T1;
    int cnt = min(T1, E - tile0);

    hist[tid] = 0; lcnt[tid] = 0;
    __syncthreads();

    int s[T1 / 256], d[T1 / 256];
#pragma unroll
    for (int i = 0; i < T1 / 256; ++i) {
        int k = i * 256 + tid;
        if (k < cnt) {
            s[i] = ei[tile0 + k];
            d[i] = ei[E + tile0 + k];
            atomicAdd(&hist[d[i] >> GSH], 1);
        }
    }
    __syncthreads();

    int h = hist[tid];
    scanbuf[tid] = h;
    __syncthreads();
    for (int off = 1; off < 256; off <<= 1) {
        int t = (tid >= (unsigned)off) ? scanbuf[tid - off] : 0;
        __syncthreads();
        scanbuf[tid] += t;
        __syncthreads();
    }
    base[tid] = scanbuf[tid] - h;
    gbase[tid] = (tid < B && h > 0) ? atomicAdd(&cursor[tid], h) : 0;
    __syncthreads();

#pragma unroll
    for (int i = 0; i < T1 / 256; ++i) {
        int k = i * 256 + tid;
        if (k < cnt) {
            int b = d[i] >> GSH;
            int pos = base[b] + atomicAdd(&lcnt[b], 1);
            pl[pos] = ((unsigned long long)(unsigned)d[i] << 32) | (unsigned)s[i];
        }
    }
    __syncthreads();

    for (int k = tid; k < cnt; k += 256) {           // linear copy-out: runs coalesce
        unsigned long long p = pl[k];
        int b = (int)(p >> (32 + GSH));
        unsigned int packed = (((unsigned int)(p >> 32) & (GRP - 1)) << 17)
                            | ((unsigned int)p & 0x1FFFFu);
        pairs[(size_t)gbase[b] + (k - base[b])] = packed;
    }
}

// ---------------- bucket-count scan -> csrBase; rowptr[N] = E ----------------

__global__ void k_bscan(const int* __restrict__ cursor, int* __restrict__ csrBase,
                        int* __restrict__ rowptr, int B, int E, int N) {
    __shared__ int sh[256];
    int t = threadIdx.x;
    int c = (t < B) ? cursor[t] - t * STRIDE : 0;
    sh[t] = c;
    __syncthreads();
    for (int off = 1; off < 256; off <<= 1) {
        int u = (t >= off) ? sh[t - off] : 0;
        __syncthreads();
        sh[t] += u;
        __syncthreads();
    }
    if (t < B) csrBase[t] = sh[t] - c;
    if (t == 0) rowptr[N] = E;
}

// ---------------- phase 2: per-bucket CSR scatter + deg/dinv/rowptr ----------------

__global__ __launch_bounds__(512) void k_p2(const unsigned int* __restrict__ pairs,
                                            const int* __restrict__ cursor,
                                            const int* __restrict__ csrBase,
                                            int* __restrict__ csr, int* __restrict__ rowptr,
                                            float* __restrict__ dinv, int N) {
    __shared__ int hist[GRP], cur[GRP], scanbuf[GRP];
    int t = threadIdx.x;
    int b = blockIdx.x;
    int v0 = b << GSH;
    size_t reg0 = (size_t)b * STRIDE;
    int cnt = cursor[b] - b * STRIDE;

    hist[t] = 0;
    __syncthreads();
    for (int k = t; k < cnt; k += GRP)
        atomicAdd(&hist[pairs[reg0 + k] >> 17], 1);
    __syncthreads();

    int h = hist[t];
    scanbuf[t] = h;
    __syncthreads();
    for (int off = 1; off < GRP; off <<= 1) {
        int u = (t >= off) ? scanbuf[t - off] : 0;
        __syncthreads();
        scanbuf[t] += u;
        __syncthreads();
    }
    int excl = scanbuf[t] - h;
    int cB = csrBase[b];
    int v = v0 + t;
    if (v < N) {
        rowptr[v] = cB + excl;
        dinv[v] = rsqrtf((float)(h + 1));
    }
    cur[t] = excl;
    __syncthreads();

    for (int k = t; k < cnt; k += GRP) {
        unsigned int p = pairs[reg0 + k];
        int l = p >> 17;
        int pos = atomicAdd(&cur[l], 1);
        csr[cB + pos] = (int)(p & 0x1FFFFu);
    }
}

// ---------------- GEMM1 (MFMA, fused fp32->bf16 + dinv scale on A) ----------------

__global__ __launch_bounds__(256) void k_gemm1(const float* __restrict__ x,
                                               const float* __restrict__ W1,
                                               const float* __restrict__ dinv,
                                               unsigned short* __restrict__ A1, int N) {
    __shared__ unsigned short Wt[EMBED * 136];       // W^T, K padded 128->136
    for (int i = threadIdx.x; i < FEAT * EMBED; i += 256) {
        int k = i >> 6, n = i & 63;
        Wt[n * 136 + k] = f2bf(W1[i]);
    }
    __syncthreads();

    int wv = threadIdx.x >> 6, lane = threadIdx.x & 63;
    int g = lane >> 4, r = lane & 15;
    int arow = blockIdx.x * 64 + wv * 16 + r;
    bool rowok = arow < N;
    float dv = rowok ? dinv[arow] : 0.f;

    s8v a[4];
#pragma unroll
    for (int ks = 0; ks < 4; ++ks) {
        if (rowok) {
            const float* p = x + (size_t)arow * FEAT + ks * 32 + g * 8;
            float4 p0 = *(const float4*)p;
            float4 p1 = *(const float4*)(p + 4);
            s8v t;
            t[0] = (short)f2bf(p0.x * dv); t[1] = (short)f2bf(p0.y * dv);
            t[2] = (short)f2bf(p0.z * dv); t[3] = (short)f2bf(p0.w * dv);
            t[4] = (short)f2bf(p1.x * dv); t[5] = (short)f2bf(p1.y * dv);
            t[6] = (short)f2bf(p1.z * dv); t[7] = (short)f2bf(p1.w * dv);
            a[ks] = t;
        } else {
            s8v z = {};
            a[ks] = z;
        }
    }

    f32x4 acc[4];
#pragma unroll
    for (int nt = 0; nt < 4; ++nt) acc[nt] = (f32x4){0.f, 0.f, 0.f, 0.f};

#pragma unroll
    for (int nt = 0; nt < 4; ++nt) {
        int n0 = nt * 16;
#pragma unroll
        for (int ks = 0; ks < 4; ++ks) {
            s8v bfr = *(const s8v*)&Wt[(n0 + r) * 136 + ks * 32 + g * 8];
            acc[nt] = __builtin_amdgcn_mfma_f32_16x16x32_bf16(a[ks], bfr, acc[nt], 0, 0, 0);
        }
    }

    int orow0 = blockIdx.x * 64 + wv * 16 + g * 4;
#pragma unroll
    for (int nt = 0; nt < 4; ++nt)
#pragma unroll
        for (int q = 0; q < 4; ++q) {
            int orow = orow0 + q;
            if (orow < N) A1[(size_t)orow * EMBED + nt * 16 + r] = f2bf(acc[nt][q]);
        }
}

// ---------------- pipelined wide gather (2 nodes/wave, UNIFORM group elision) ----------------
// rs = lane>>3 (slot 0..7), dp = (lane&7)*8 (8 dims = 16B per lane).
// Virtual index list per node: positions 0..cnt-2 = csr[beg..], cnt-1 = self.
// cnt is wave-uniform (all lanes load the same rowptr words) -> readfirstlane
// makes it an SGPR, so group conditionals compile to s_cmp+s_cbranch (scalar
// skip, NO exec-mask churn — round-11's mistake was VGPR-resident conditions).
// Skipping a group saves its VMEM instruction AND its 64-wide accumulate.

struct I4 { int s0, s1, s2, s3; };

static __device__ __forceinline__ I4 g_idx(const int* __restrict__ csr,
                                           int beg, int cnt, int v, int rs) {
    I4 r;
    r.s0 = (rs      < cnt - 1) ? csr[beg + rs]      : v;
    r.s1 = (rs + 8  < cnt - 1) ? csr[beg + rs + 8]  : v;
    r.s2 = (rs + 16 < cnt - 1) ? csr[beg + rs + 16] : v;
    r.s3 = (rs + 24 < cnt - 1) ? csr[beg + rs + 24] : v;
    return r;
}
static __device__ __forceinline__ void accu(float* a, s8v u) {
#pragma unroll
    for (int i = 0; i < 8; ++i) a[i] += bf2f((unsigned short)u[i]);
}
static __device__ __forceinline__ void g_tail(const unsigned short* __restrict__ T,
                                              const int* __restrict__ csr,
                                              int beg, int cnt, int v, int rs, int dp,
                                              float* a) {
    for (int p = 32 + rs; p < cnt; p += 8) {
        int s = (p < cnt - 1) ? csr[beg + p] : v;
        s8v u = *(const s8v*)(T + (size_t)s * EMBED + dp);
        accu(a, u);
    }
}
static __device__ __forceinline__ void fold8(float* a) {
#pragma unroll
    for (int o = 8; o < 64; o <<= 1) {
#pragma unroll
        for (int i = 0; i < 8; ++i) a[i] += __shfl_xor(a[i], o);
    }
}

// Core: idx loads unconditional (cheap, consecutive ints); row loads + accu
// per group under wave-uniform (SGPR) conditions; all loads before all accu.
#define GATHER2U(TBL)                                                            \
    int ucA = __builtin_amdgcn_readfirstlane(cntA);                              \
    int ucB = __builtin_amdgcn_readfirstlane(cntB);                              \
    I4 iA = g_idx(csr, begA, cntA, va, rs);                                      \
    I4 iB = g_idx(csr, begB, cntB, vB, rs);                                      \
    float aA[8] = {0,0,0,0,0,0,0,0}, aB[8] = {0,0,0,0,0,0,0,0};                  \
    s8v uA0, uA1, uA2, uA3, uB0, uB1, uB2, uB3;                                  \
    uA0 = *(const s8v*)(TBL + (size_t)iA.s0 * EMBED + dp);                       \
    uB0 = *(const s8v*)(TBL + (size_t)iB.s0 * EMBED + dp);                       \
    if (ucA > 8)  uA1 = *(const s8v*)(TBL + (size_t)iA.s1 * EMBED + dp);         \
    if (ucB > 8)  uB1 = *(const s8v*)(TBL + (size_t)iB.s1 * EMBED + dp);         \
    if (ucA > 16) uA2 = *(const s8v*)(TBL + (size_t)iA.s2 * EMBED + dp);         \
    if (ucB > 16) uB2 = *(const s8v*)(TBL + (size_t)iB.s2 * EMBED + dp);         \
    if (ucA > 24) uA3 = *(const s8v*)(TBL + (size_t)iA.s3 * EMBED + dp);         \
    if (ucB > 24) uB3 = *(const s8v*)(TBL + (size_t)iB.s3 * EMBED + dp);         \
    if (rs < ucA) accu(aA, uA0);                                                 \
    if (rs < ucB) accu(aB, uB0);                                                 \
    if (ucA > 8)  { if (rs + 8  < ucA) accu(aA, uA1); }                          \
    if (ucB > 8)  { if (rs + 8  < ucB) accu(aB, uB1); }                          \
    if (ucA > 16) { if (rs + 16 < ucA) accu(aA, uA2); }                          \
    if (ucB > 16) { if (rs + 16 < ucB) accu(aB, uB2); }                          \
    if (ucA > 24) { if (rs + 24 < ucA) accu(aA, uA3); }                          \
    if (ucB > 24) { if (rs + 24 < ucB) accu(aB, uB3); }                          \
    if (ucA > 32) g_tail(TBL, csr, begA, ucA, va, rs, dp, aA);                   \
    if (ucB > 32) g_tail(TBL, csr, begB, ucB, vB, rs, dp, aB);                   \
    fold8(aA);                                                                   \
    fold8(aB);

// gather layer 1: Hb = bf16( dinv * relu(dinv*sum + b1) )   (sum includes self)
__global__ __launch_bounds__(256) void k_gf1(const int* __restrict__ rowptr,
                                             const int* __restrict__ csr,
                                             const unsigned short* __restrict__ A1,
                                             const float* __restrict__ dinv,
                                             const float* __restrict__ b1,
                                             unsigned short* __restrict__ Hb, int N) {
    int wv = threadIdx.x >> 6, lane = threadIdx.x & 63;
    int va = (blockIdx.x * 4 + wv) * 2;
    if (va >= N) return;
    int vb = va + 1;
    bool okB = vb < N;
    int vB = okB ? vb : va;
    int rs = lane >> 3, dp = (lane & 7) * 8;

    int2 rp01 = *(const int2*)(rowptr + va);         // va even -> 8B aligned
    int rp2 = okB ? rowptr[vb + 1] : rp01.y;
    float dvA = dinv[va];
    float dvB = okB ? dinv[vb] : 0.f;
    float4 bL = *(const float4*)(b1 + dp);
    float4 bH = *(const float4*)(b1 + dp + 4);

    int begA = rp01.x, cntA = rp01.y - rp01.x + 1;
    int begB = rp01.y, cntB = okB ? (rp2 - rp01.y + 1) : 0;

    GATHER2U(A1)

    if (rs == 0) {
        s8v o;
        float h;
        h = fmaxf(dvA * aA[0] + bL.x, 0.f); o[0] = (short)f2bf(h * dvA);
        h = fmaxf(dvA * aA[1] + bL.y, 0.f); o[1] = (short)f2bf(h * dvA);
        h = fmaxf(dvA * aA[2] + bL.z, 0.f); o[2] = (short)f2bf(h * dvA);
        h = fmaxf(dvA * aA[3] + bL.w, 0.f); o[3] = (short)f2bf(h * dvA);
        h = fmaxf(dvA * aA[4] + bH.x, 0.f); o[4] = (short)f2bf(h * dvA);
        h = fmaxf(dvA * aA[5] + bH.y, 0.f); o[5] = (short)f2bf(h * dvA);
        h = fmaxf(dvA * aA[6] + bH.z, 0.f); o[6] = (short)f2bf(h * dvA);
        h = fmaxf(dvA * aA[7] + bH.w, 0.f); o[7] = (short)f2bf(h * dvA);
        *(s8v*)(Hb + (size_t)va * EMBED + dp) = o;
        if (okB) {
            s8v p;
            h = fmaxf(dvB * aB[0] + bL.x, 0.f); p[0] = (short)f2bf(h * dvB);
            h = fmaxf(dvB * aB[1] + bL.y, 0.f); p[1] = (short)f2bf(h * dvB);
            h = fmaxf(dvB * aB[2] + bL.z, 0.f); p[2] = (short)f2bf(h * dvB);
            h = fmaxf(dvB * aB[3] + bL.w, 0.f); p[3] = (short)f2bf(h * dvB);
            h = fmaxf(dvB * aB[4] + bH.x, 0.f); p[4] = (short)f2bf(h * dvB);
            h = fmaxf(dvB * aB[5] + bH.y, 0.f); p[5] = (short)f2bf(h * dvB);
            h = fmaxf(dvB * aB[6] + bH.z, 0.f); p[6] = (short)f2bf(h * dvB);
            h = fmaxf(dvB * aB[7] + bH.w, 0.f); p[7] = (short)f2bf(h * dvB);
            *(s8v*)(Hb + (size_t)vb * EMBED + dp) = p;
        }
    }
}

// gather layer 2 (linearity): Pb = bf16( dinv[v] * sum Hb )   (sum includes self)
__global__ __launch_bounds__(256) void k_gf2h(const int* __restrict__ rowptr,
                                              const int* __restrict__ csr,
                                              const unsigned short* __restrict__ Hb,
                                              const float* __restrict__ dinv,
                                              unsigned short* __restrict__ Pb, int N) {
    int wv = threadIdx.x >> 6, lane = threadIdx.x & 63;
    int va = (blockIdx.x * 4 + wv) * 2;
    if (va >= N) return;
    int vb = va + 1;
    bool okB = vb < N;
    int vB = okB ? vb : va;
    int rs = lane >> 3, dp = (lane & 7) * 8;

    int2 rp01 = *(const int2*)(rowptr + va);
    int rp2 = okB ? rowptr[vb + 1] : rp01.y;
    float dvA = dinv[va];
    float dvB = okB ? dinv[vb] : 0.f;

    int begA = rp01.x, cntA = rp01.y - rp01.x + 1;
    int begB = rp01.y, cntB = okB ? (rp2 - rp01.y + 1) : 0;

    GATHER2U(Hb)

    if (rs == 0) {
        s8v o;
#pragma unroll
        for (int i = 0; i < 8; ++i) o[i] = (short)f2bf(dvA * aA[i]);
        *(s8v*)(Pb + (size_t)va * EMBED + dp) = o;
        if (okB) {
            s8v p;
#pragma unroll
            for (int i = 0; i < 8; ++i) p[i] = (short)f2bf(dvB * aB[i]);
            *(s8v*)(Pb + (size_t)vb * EMBED + dp) = p;
        }
    }
}

// ---------------- final: out = log_softmax(Pb @ W2 + b2) (MFMA + fused softmax) ----------------

__global__ __launch_bounds__(256) void k_fin(const unsigned short* __restrict__ Pb,
                                             const float* __restrict__ W2,
                                             const float* __restrict__ b2,
                                             float* __restrict__ out, int N) {
    __shared__ unsigned short Wt[48 * 72];           // W2^T, cols padded 40->48, K 64->72
    for (int i = threadIdx.x; i < 48 * EMBED; i += 256) {
        int n = i >> 6, k = i & 63;
        Wt[n * 72 + k] = (n < CLS) ? f2bf(W2[k * CLS + n]) : 0;
    }
    __syncthreads();

    int wv = threadIdx.x >> 6, lane = threadIdx.x & 63;
    int g = lane >> 4, r = lane & 15;
    int arow = blockIdx.x * 64 + wv * 16 + r;

    s8v z = {};
    s8v a[2];
#pragma unroll
    for (int ks = 0; ks < 2; ++ks)
        a[ks] = (arow < N) ? *(const s8v*)(Pb + (size_t)arow * EMBED + ks * 32 + g * 8) : z;

    f32x4 acc[3];
#pragma unroll
    for (int nt = 0; nt < 3; ++nt) acc[nt] = (f32x4){0.f, 0.f, 0.f, 0.f};

#pragma unroll
    for (int nt = 0; nt < 3; ++nt)
#pragma unroll
        for (int ks = 0; ks < 2; ++ks) {
            s8v bfr = *(const s8v*)&Wt[(nt * 16 + r) * 72 + ks * 32 + g * 8];
            acc[nt] = __builtin_amdgcn_mfma_f32_16x16x32_bf16(a[ks], bfr, acc[nt], 0, 0, 0);
        }

    int orow0 = blockIdx.x * 64 + wv * 16 + g * 4;
    bool v2 = r < (CLS - 32);
#pragma unroll
    for (int q = 0; q < 4; ++q) {
        float l0 = acc[0][q] + b2[r];
        float l1 = acc[1][q] + b2[16 + r];
        float l2 = v2 ? acc[2][q] + b2[32 + r] : -INFINITY;
        float m = fmaxf(fmaxf(l0, l1), l2);
#pragma unroll
        for (int o = 1; o < 16; o <<= 1) m = fmaxf(m, __shfl_xor(m, o));
        float se = __expf(l0 - m) + __expf(l1 - m) + (v2 ? __expf(l2 - m) : 0.f);
#pragma unroll
        for (int o = 1; o < 16; o <<= 1) se += __shfl_xor(se, o);
        float lse = m + __logf(se);
        int orow = orow0 + q;
        if (orow < N) {
            float* op = out + (size_t)orow * CLS;
            op[r] = l0 - lse;
            op[16 + r] = l1 - lse;
            if (v2) op[32 + r] = l2 - lse;
        }
    }
}

// ---------------- launch ----------------

extern "C" void kernel_launch(void* const* d_in, const int* in_sizes, int n_in,
                              void* d_out, int out_size, void* d_ws, size_t ws_size,
                              hipStream_t stream) {
    const float* x  = (const float*)d_in[0];
    const int*   ei = (const int*)d_in[1];
    const float* W1 = (const float*)d_in[2];
    const float* b1 = (const float*)d_in[3];
    const float* W2 = (const float*)d_in[4];
    const float* b2 = (const float*)d_in[5];
    float* out = (float*)d_out;

    const int N = in_sizes[0] / FEAT;           // 100000  (< 2^17 for pair packing)
    const int E = in_sizes[1] / 2;              // 1600000
    const int B = (N + GRP - 1) >> GSH;         // 196 buckets (<=256)

    char* ws = (char*)d_ws;
    size_t off = 0;
    auto alloc = [&](size_t bytes) { char* p = ws + off; off = (off + bytes + 255) & ~(size_t)255; return p; };
    int*   cursor  = (int*)alloc(256 * 4);
    int*   csrBase = (int*)alloc(256 * 4);
    float* dinv    = (float*)alloc((size_t)N * 4);
    int*   rowptr  = (int*)alloc((size_t)(N + 1) * 4);
    int*   csr     = (int*)alloc((size_t)E * 4);
    // union region: packed pairs (9.6 MB) dead before A1/Hb written (25.6 MB);
    // Pb aliases A1 (A1 dead after gf1; gf2h reads Hb, writes Pb in disjoint half)
    size_t regA = (size_t)B * STRIDE * 4;
    size_t regB = (size_t)N * EMBED * 4;        // A1 + Hb
    char*  region = alloc(regA > regB ? regA : regB);
    unsigned int*   pairs = (unsigned int*)region;
    unsigned short* A1 = (unsigned short*)region;
    unsigned short* Hb = (unsigned short*)(region + (size_t)N * EMBED * 2);
    unsigned short* Pb = A1;

    k_initcur<<<1, 256, 0, stream>>>(cursor, B);
    k_p1<<<(E + T1 - 1) / T1, 256, 0, stream>>>(ei, pairs, cursor, E, B);
    k_bscan<<<1, 256, 0, stream>>>(cursor, csrBase, rowptr, B, E, N);
    k_p2<<<B, GRP, 0, stream>>>(pairs, cursor, csrBase, csr, rowptr, dinv, N);

    k_gemm1<<<(N + 63) / 64, 256, 0, stream>>>(x, W1, dinv, A1, N);
    k_gf1<<<(N + 7) / 8, 256, 0, stream>>>(rowptr, csr, A1, dinv, b1, Hb, N);
    k_gf2h<<<(N + 7) / 8, 256, 0, stream>>>(rowptr, csr, Hb, dinv, Pb, N);
    k_fin<<<(N + 63) / 64, 256, 0, stream>>>(Pb, W2, b2, out, N);
}

// Round 14
// 140.438 us; speedup vs baseline: 1.2251x; 1.2251x over previous
//
#include <hip/hip_runtime.h>
#include <math.h>

#define FEAT 128
#define EMBED 64
#define CLS 40

#define GRP 512          // nodes per bucket (pow2)
#define GSH 9            // log2(GRP)
#define STRIDE 12288     // pairs-buffer slots per bucket (mean fill ~8163)
#define T1 2048          // edges per phase-1 tile

typedef __attribute__((ext_vector_type(8))) short s8v;    // 8 bf16
typedef __attribute__((ext_vector_type(4))) float f32x4;  // MFMA acc

static __device__ __forceinline__ float bf2f(unsigned short u) {
    union { unsigned int i; float f; } c; c.i = ((unsigned int)u) << 16; return c.f;
}
static __device__ __forceinline__ unsigned short f2bf(float f) {
    union { float f; unsigned int i; } c; c.f = f;
    unsigned int x = c.i;
    x += 0x7fffu + ((x >> 16) & 1u);   // RNE
    return (unsigned short)(x >> 16);
}

// ---------------- cursor init ----------------

__global__ void k_initcur(int* __restrict__ cursor, int B) {
    int t = blockIdx.x * blockDim.x + threadIdx.x;
    if (t < B) cursor[t] = t * STRIDE;
}

// ---------------- phase 1: LDS counting-sort tiles into bucketed packed pairs ----------------
// packed pair: bits 25..17 = dst&511 (bucket-local), bits 16..0 = src  (N < 2^17)

__global__ __launch_bounds__(256) void k_p1(const int* __restrict__ ei,
                                            unsigned int* __restrict__ pairs,
                                            int* __restrict__ cursor, int E, int B) {
    __shared__ unsigned long long pl[T1];            // 16 KB (needs full dst for bucket)
    __shared__ int hist[256], base[256], gbase[256], lcnt[256], scanbuf[256];
    int tid = threadIdx.x;
    int tile0 = blockIdx.x * T1;
    int cnt = min(T1, E - tile0);

    hist[tid] = 0; lcnt[tid] = 0;
    __syncthreads();

    int s[T1 / 256], d[T1 / 256];
#pragma unroll
    for (int i = 0; i < T1 / 256; ++i) {
        int k = i * 256 + tid;
        if (k < cnt) {
            s[i] = ei[tile0 + k];
            d[i] = ei[E + tile0 + k];
            atomicAdd(&hist[d[i] >> GSH], 1);
        }
    }
    __syncthreads();

    int h = hist[tid];
    scanbuf[tid] = h;
    __syncthreads();
    for (int off = 1; off < 256; off <<= 1) {
        int t = (tid >= (unsigned)off) ? scanbuf[tid - off] : 0;
        __syncthreads();
        scanbuf[tid] += t;
        __syncthreads();
    }
    base[tid] = scanbuf[tid] - h;
    gbase[tid] = (tid < B && h > 0) ? atomicAdd(&cursor[tid], h) : 0;
    __syncthreads();

#pragma unroll
    for (int i = 0; i < T1 / 256; ++i) {
        int k = i * 256 + tid;
        if (k < cnt) {
            int b = d[i] >> GSH;
            int pos = base[b] + atomicAdd(&lcnt[b], 1);
            pl[pos] = ((unsigned long long)(unsigned)d[i] << 32) | (unsigned)s[i];
        }
    }
    __syncthreads();

    for (int k = tid; k < cnt; k += 256) {           // linear copy-out: runs coalesce
        unsigned long long p = pl[k];
        int b = (int)(p >> (32 + GSH));
        unsigned int packed = (((unsigned int)(p >> 32) & (GRP - 1)) << 17)
                            | ((unsigned int)p & 0x1FFFFu);
        pairs[(size_t)gbase[b] + (k - base[b])] = packed;
    }
}

// ---------------- bucket-count scan -> csrBase; rowptr[N] = E ----------------

__global__ void k_bscan(const int* __restrict__ cursor, int* __restrict__ csrBase,
                        int* __restrict__ rowptr, int B, int E, int N) {
    __shared__ int sh[256];
    int t = threadIdx.x;
    int c = (t < B) ? cursor[t] - t * STRIDE : 0;
    sh[t] = c;
    __syncthreads();
    for (int off = 1; off < 256; off <<= 1) {
        int u = (t >= off) ? sh[t - off] : 0;
        __syncthreads();
        sh[t] += u;
        __syncthreads();
    }
    if (t < B) csrBase[t] = sh[t] - c;
    if (t == 0) rowptr[N] = E;
}

// ---------------- phase 2: per-bucket CSR scatter + deg/dinv/rowptr ----------------

__global__ __launch_bounds__(512) void k_p2(const unsigned int* __restrict__ pairs,
                                            const int* __restrict__ cursor,
                                            const int* __restrict__ csrBase,
                                            int* __restrict__ csr, int* __restrict__ rowptr,
                                            float* __restrict__ dinv, int N) {
    __shared__ int hist[GRP], cur[GRP], scanbuf[GRP];
    int t = threadIdx.x;
    int b = blockIdx.x;
    int v0 = b << GSH;
    size_t reg0 = (size_t)b * STRIDE;
    int cnt = cursor[b] - b * STRIDE;

    hist[t] = 0;
    __syncthreads();
    for (int k = t; k < cnt; k += GRP)
        atomicAdd(&hist[pairs[reg0 + k] >> 17], 1);
    __syncthreads();

    int h = hist[t];
    scanbuf[t] = h;
    __syncthreads();
    for (int off = 1; off < GRP; off <<= 1) {
        int u = (t >= off) ? scanbuf[t - off] : 0;
        __syncthreads();
        scanbuf[t] += u;
        __syncthreads();
    }
    int excl = scanbuf[t] - h;
    int cB = csrBase[b];
    int v = v0 + t;
    if (v < N) {
        rowptr[v] = cB + excl;
        dinv[v] = rsqrtf((float)(h + 1));
    }
    cur[t] = excl;
    __syncthreads();

    for (int k = t; k < cnt; k += GRP) {
        unsigned int p = pairs[reg0 + k];
        int l = p >> 17;
        int pos = atomicAdd(&cur[l], 1);
        csr[cB + pos] = (int)(p & 0x1FFFFu);
    }
}

// ---------------- GEMM1 (MFMA, fused fp32->bf16 + dinv scale on A) ----------------

__global__ __launch_bounds__(256) void k_gemm1(const float* __restrict__ x,
                                               const float* __restrict__ W1,
                                               const float* __restrict__ dinv,
                                               unsigned short* __restrict__ A1, int N) {
    __shared__ unsigned short Wt[EMBED * 136];       // W^T, K padded 128->136
    for (int i = threadIdx.x; i < FEAT * EMBED; i += 256) {
        int k = i >> 6, n = i & 63;
        Wt[n * 136 + k] = f2bf(W1[i]);
    }
    __syncthreads();

    int wv = threadIdx.x >> 6, lane = threadIdx.x & 63;
    int g = lane >> 4, r = lane & 15;
    int arow = blockIdx.x * 64 + wv * 16 + r;
    bool rowok = arow < N;
    float dv = rowok ? dinv[arow] : 0.f;

    s8v a[4];
#pragma unroll
    for (int ks = 0; ks < 4; ++ks) {
        if (rowok) {
            const float* p = x + (size_t)arow * FEAT + ks * 32 + g * 8;
            float4 p0 = *(const float4*)p;
            float4 p1 = *(const float4*)(p + 4);
            s8v t;
            t[0] = (short)f2bf(p0.x * dv); t[1] = (short)f2bf(p0.y * dv);
            t[2] = (short)f2bf(p0.z * dv); t[3] = (short)f2bf(p0.w * dv);
            t[4] = (short)f2bf(p1.x * dv); t[5] = (short)f2bf(p1.y * dv);
            t[6] = (short)f2bf(p1.z * dv); t[7] = (short)f2bf(p1.w * dv);
            a[ks] = t;
        } else {
            s8v z = {};
            a[ks] = z;
        }
    }

    f32x4 acc[4];
#pragma unroll
    for (int nt = 0; nt < 4; ++nt) acc[nt] = (f32x4){0.f, 0.f, 0.f, 0.f};

#pragma unroll
    for (int nt = 0; nt < 4; ++nt) {
        int n0 = nt * 16;
#pragma unroll
        for (int ks = 0; ks < 4; ++ks) {
            s8v bfr = *(const s8v*)&Wt[(n0 + r) * 136 + ks * 32 + g * 8];
            acc[nt] = __builtin_amdgcn_mfma_f32_16x16x32_bf16(a[ks], bfr, acc[nt], 0, 0, 0);
        }
    }

    int orow0 = blockIdx.x * 64 + wv * 16 + g * 4;
#pragma unroll
    for (int nt = 0; nt < 4; ++nt)
#pragma unroll
        for (int q = 0; q < 4; ++q) {
            int orow = orow0 + q;
            if (orow < N) A1[(size_t)orow * EMBED + nt * 16 + r] = f2bf(acc[nt][q]);
        }
}

// ---------------- pipelined wide gather (2 nodes/wave, straight-line loads) ----------------
// rs = lane>>3 (slot 0..7), dp = (lane&7)*8 (8 dims = 16B per lane).
// Virtual index list per node: positions 0..cnt-2 = csr[beg..], cnt-1 = self.
// ALL loads unconditional (masked slots point at the self row): keeps the
// idx + row loads in one straight-line clause — no exec-mask branching.
// (Rounds 9/11/13 lesson: ANY branch form around the row-load clause —
// divergent OR readfirstlane-scalar — loses 20-25%. Keep it branch-free.)
// 3 static groups (24 slots) instead of 4: E[groups needed]=2.56 at
// deg~Poisson(16); P(cnt>24)=3.4% goes through the rare tail loop.

struct I3 { int s0, s1, s2; };
struct R3 { s8v u0, u1, u2; };

static __device__ __forceinline__ I3 g_idx(const int* __restrict__ csr,
                                           int beg, int cnt, int v, int rs) {
    I3 r;
    r.s0 = (rs      < cnt - 1) ? csr[beg + rs]      : v;
    r.s1 = (rs + 8  < cnt - 1) ? csr[beg + rs + 8]  : v;
    r.s2 = (rs + 16 < cnt - 1) ? csr[beg + rs + 16] : v;
    return r;
}
static __device__ __forceinline__ R3 g_rows(const unsigned short* __restrict__ T,
                                            const I3& i, int dp) {
    R3 r;
    r.u0 = *(const s8v*)(T + (size_t)i.s0 * EMBED + dp);
    r.u1 = *(const s8v*)(T + (size_t)i.s1 * EMBED + dp);
    r.u2 = *(const s8v*)(T + (size_t)i.s2 * EMBED + dp);
    return r;
}
// accumulate 8 bf16 into 8 f32 at 2 VALU/elem: per dword, lo = w<<16,
// hi = w & 0xffff0000 (exact same bits as bf2f on each ushort).
static __device__ __forceinline__ void accu(float* a, s8v u) {
    union { s8v v; unsigned int w[4]; } c;
    c.v = u;
#pragma unroll
    for (int i = 0; i < 4; ++i) {
        union { unsigned int i; float f; } lo, hi;
        lo.i = c.w[i] << 16;
        hi.i = c.w[i] & 0xffff0000u;
        a[2 * i]     += lo.f;
        a[2 * i + 1] += hi.f;
    }
}
static __device__ __forceinline__ void g_acc(const R3& r, int rs, int cnt, float* a) {
    if (rs < cnt)      accu(a, r.u0);
    if (rs + 8 < cnt)  accu(a, r.u1);
    if (rs + 16 < cnt) accu(a, r.u2);
}
static __device__ __forceinline__ void g_tail(const unsigned short* __restrict__ T,
                                              const int* __restrict__ csr,
                                              int beg, int cnt, int v, int rs, int dp,
                                              float* a) {
    for (int p = 24 + rs; p < cnt; p += 8) {
        int s = (p < cnt - 1) ? csr[beg + p] : v;
        s8v u = *(const s8v*)(T + (size_t)s * EMBED + dp);
        accu(a, u);
    }
}
static __device__ __forceinline__ void fold8(float* a) {
#pragma unroll
    for (int o = 8; o < 64; o <<= 1) {
#pragma unroll
        for (int i = 0; i < 8; ++i) a[i] += __shfl_xor(a[i], o);
    }
}

// gather layer 1: Hb = bf16( dinv * relu(dinv*sum + b1) )   (sum includes self)
__global__ __launch_bounds__(256) void k_gf1(const int* __restrict__ rowptr,
                                             const int* __restrict__ csr,
                                             const unsigned short* __restrict__ A1,
                                             const float* __restrict__ dinv,
                                             const float* __restrict__ b1,
                                             unsigned short* __restrict__ Hb, int N) {
    int wv = threadIdx.x >> 6, lane = threadIdx.x & 63;
    int va = (blockIdx.x * 4 + wv) * 2;
    if (va >= N) return;
    int vb = va + 1;
    bool okB = vb < N;
    int vB = okB ? vb : va;
    int rs = lane >> 3, dp = (lane & 7) * 8;

    int2 rp01 = *(const int2*)(rowptr + va);         // va even -> 8B aligned
    int rp2 = okB ? rowptr[vb + 1] : rp01.y;
    float dvA = dinv[va];
    float dvB = okB ? dinv[vb] : 0.f;
    float4 bL = *(const float4*)(b1 + dp);
    float4 bH = *(const float4*)(b1 + dp + 4);

    int begA = rp01.x, cntA = rp01.y - rp01.x + 1;
    int begB = rp01.y, cntB = okB ? (rp2 - rp01.y + 1) : 0;

    I3 iA = g_idx(csr, begA, cntA, va, rs);
    I3 iB = g_idx(csr, begB, cntB, vB, rs);
    R3 rA = g_rows(A1, iA, dp);
    R3 rB = g_rows(A1, iB, dp);

    float aA[8] = {0,0,0,0,0,0,0,0}, aB[8] = {0,0,0,0,0,0,0,0};
    g_acc(rA, rs, cntA, aA);
    g_acc(rB, rs, cntB, aB);
    if (cntA > 24) g_tail(A1, csr, begA, cntA, va, rs, dp, aA);
    if (cntB > 24) g_tail(A1, csr, begB, cntB, vB, rs, dp, aB);

    fold8(aA);
    fold8(aB);

    if (rs == 0) {
        s8v o;
        float h;
        h = fmaxf(dvA * aA[0] + bL.x, 0.f); o[0] = (short)f2bf(h * dvA);
        h = fmaxf(dvA * aA[1] + bL.y, 0.f); o[1] = (short)f2bf(h * dvA);
        h = fmaxf(dvA * aA[2] + bL.z, 0.f); o[2] = (short)f2bf(h * dvA);
        h = fmaxf(dvA * aA[3] + bL.w, 0.f); o[3] = (short)f2bf(h * dvA);
        h = fmaxf(dvA * aA[4] + bH.x, 0.f); o[4] = (short)f2bf(h * dvA);
        h = fmaxf(dvA * aA[5] + bH.y, 0.f); o[5] = (short)f2bf(h * dvA);
        h = fmaxf(dvA * aA[6] + bH.z, 0.f); o[6] = (short)f2bf(h * dvA);
        h = fmaxf(dvA * aA[7] + bH.w, 0.f); o[7] = (short)f2bf(h * dvA);
        *(s8v*)(Hb + (size_t)va * EMBED + dp) = o;
        if (okB) {
            s8v p;
            h = fmaxf(dvB * aB[0] + bL.x, 0.f); p[0] = (short)f2bf(h * dvB);
            h = fmaxf(dvB * aB[1] + bL.y, 0.f); p[1] = (short)f2bf(h * dvB);
            h = fmaxf(dvB * aB[2] + bL.z, 0.f); p[2] = (short)f2bf(h * dvB);
            h = fmaxf(dvB * aB[3] + bL.w, 0.f); p[3] = (short)f2bf(h * dvB);
            h = fmaxf(dvB * aB[4] + bH.x, 0.f); p[4] = (short)f2bf(h * dvB);
            h = fmaxf(dvB * aB[5] + bH.y, 0.f); p[5] = (short)f2bf(h * dvB);
            h = fmaxf(dvB * aB[6] + bH.z, 0.f); p[6] = (short)f2bf(h * dvB);
            h = fmaxf(dvB * aB[7] + bH.w, 0.f); p[7] = (short)f2bf(h * dvB);
            *(s8v*)(Hb + (size_t)vb * EMBED + dp) = p;
        }
    }
}

// gather layer 2 (linearity): Pb = bf16( dinv[v] * sum Hb )   (sum includes self)
__global__ __launch_bounds__(256) void k_gf2h(const int* __restrict__ rowptr,
                                              const int* __restrict__ csr,
                                              const unsigned short* __restrict__ Hb,
                                              const float* __restrict__ dinv,
                                              unsigned short* __restrict__ Pb, int N) {
    int wv = threadIdx.x >> 6, lane = threadIdx.x & 63;
    int va = (blockIdx.x * 4 + wv) * 2;
    if (va >= N) return;
    int vb = va + 1;
    bool okB = vb < N;
    int vB = okB ? vb : va;
    int rs = lane >> 3, dp = (lane & 7) * 8;

    int2 rp01 = *(const int2*)(rowptr + va);
    int rp2 = okB ? rowptr[vb + 1] : rp01.y;
    float dvA = dinv[va];
    float dvB = okB ? dinv[vb] : 0.f;

    int begA = rp01.x, cntA = rp01.y - rp01.x + 1;
    int begB = rp01.y, cntB = okB ? (rp2 - rp01.y + 1) : 0;

    I3 iA = g_idx(csr, begA, cntA, va, rs);
    I3 iB = g_idx(csr, begB, cntB, vB, rs);
    R3 rA = g_rows(Hb, iA, dp);
    R3 rB = g_rows(Hb, iB, dp);

    float aA[8] = {0,0,0,0,0,0,0,0}, aB[8] = {0,0,0,0,0,0,0,0};
    g_acc(rA, rs, cntA, aA);
    g_acc(rB, rs, cntB, aB);
    if (cntA > 24) g_tail(Hb, csr, begA, cntA, va, rs, dp, aA);
    if (cntB > 24) g_tail(Hb, csr, begB, cntB, vB, rs, dp, aB);

    fold8(aA);
    fold8(aB);

    if (rs == 0) {
        s8v o;
#pragma unroll
        for (int i = 0; i < 8; ++i) o[i] = (short)f2bf(dvA * aA[i]);
        *(s8v*)(Pb + (size_t)va * EMBED + dp) = o;
        if (okB) {
            s8v p;
#pragma unroll
            for (int i = 0; i < 8; ++i) p[i] = (short)f2bf(dvB * aB[i]);
            *(s8v*)(Pb + (size_t)vb * EMBED + dp) = p;
        }
    }
}

// ---------------- final: out = log_softmax(Pb @ W2 + b2) (MFMA + fused softmax) ----------------

__global__ __launch_bounds__(256) void k_fin(const unsigned short* __restrict__ Pb,
                                             const float* __restrict__ W2,
                                             const float* __restrict__ b2,
                                             float* __restrict__ out, int N) {
    __shared__ unsigned short Wt[48 * 72];           // W2^T, cols padded 40->48, K 64->72
    for (int i = threadIdx.x; i < 48 * EMBED; i += 256) {
        int n = i >> 6, k = i & 63;
        Wt[n * 72 + k] = (n < CLS) ? f2bf(W2[k * CLS + n]) : 0;
    }
    __syncthreads();

    int wv = threadIdx.x >> 6, lane = threadIdx.x & 63;
    int g = lane >> 4, r = lane & 15;
    int arow = blockIdx.x * 64 + wv * 16 + r;

    s8v z = {};
    s8v a[2];
#pragma unroll
    for (int ks = 0; ks < 2; ++ks)
        a[ks] = (arow < N) ? *(const s8v*)(Pb + (size_t)arow * EMBED + ks * 32 + g * 8) : z;

    f32x4 acc[3];
#pragma unroll
    for (int nt = 0; nt < 3; ++nt) acc[nt] = (f32x4){0.f, 0.f, 0.f, 0.f};

#pragma unroll
    for (int nt = 0; nt < 3; ++nt)
#pragma unroll
        for (int ks = 0; ks < 2; ++ks) {
            s8v bfr = *(const s8v*)&Wt[(nt * 16 + r) * 72 + ks * 32 + g * 8];
            acc[nt] = __builtin_amdgcn_mfma_f32_16x16x32_bf16(a[ks], bfr, acc[nt], 0, 0, 0);
        }

    int orow0 = blockIdx.x * 64 + wv * 16 + g * 4;
    bool v2 = r < (CLS - 32);
#pragma unroll
    for (int q = 0; q < 4; ++q) {
        float l0 = acc[0][q] + b2[r];
        float l1 = acc[1][q] + b2[16 + r];
        float l2 = v2 ? acc[2][q] + b2[32 + r] : -INFINITY;
        float m = fmaxf(fmaxf(l0, l1), l2);
#pragma unroll
        for (int o = 1; o < 16; o <<= 1) m = fmaxf(m, __shfl_xor(m, o));
        float se = __expf(l0 - m) + __expf(l1 - m) + (v2 ? __expf(l2 - m) : 0.f);
#pragma unroll
        for (int o = 1; o < 16; o <<= 1) se += __shfl_xor(se, o);
        float lse = m + __logf(se);
        int orow = orow0 + q;
        if (orow < N) {
            float* op = out + (size_t)orow * CLS;
            op[r] = l0 - lse;
            op[16 + r] = l1 - lse;
            if (v2) op[32 + r] = l2 - lse;
        }
    }
}

// ---------------- launch ----------------

extern "C" void kernel_launch(void* const* d_in, const int* in_sizes, int n_in,
                              void* d_out, int out_size, void* d_ws, size_t ws_size,
                              hipStream_t stream) {
    const float* x  = (const float*)d_in[0];
    const int*   ei = (const int*)d_in[1];
    const float* W1 = (const float*)d_in[2];
    const float* b1 = (const float*)d_in[3];
    const float* W2 = (const float*)d_in[4];
    const float* b2 = (const float*)d_in[5];
    float* out = (float*)d_out;

    const int N = in_sizes[0] / FEAT;           // 100000  (< 2^17 for pair packing)
    const int E = in_sizes[1] / 2;              // 1600000
    const int B = (N + GRP - 1) >> GSH;         // 196 buckets (<=256)

    char* ws = (char*)d_ws;
    size_t off = 0;
    auto alloc = [&](size_t bytes) { char* p = ws + off; off = (off + bytes + 255) & ~(size_t)255; return p; };
    int*   cursor  = (int*)alloc(256 * 4);
    int*   csrBase = (int*)alloc(256 * 4);
    float* dinv    = (float*)alloc((size_t)N * 4);
    int*   rowptr  = (int*)alloc((size_t)(N + 1) * 4);
    int*   csr     = (int*)alloc((size_t)E * 4);
    // union region: packed pairs (9.6 MB) dead before A1/Hb written (25.6 MB);
    // Pb aliases A1 (A1 dead after gf1; gf2h reads Hb, writes Pb in disjoint half)
    size_t regA = (size_t)B * STRIDE * 4;
    size_t regB = (size_t)N * EMBED * 4;        // A1 + Hb
    char*  region = alloc(regA > regB ? regA : regB);
    unsigned int*   pairs = (unsigned int*)region;
    unsigned short* A1 = (unsigned short*)region;
    unsigned short* Hb = (unsigned short*)(region + (size_t)N * EMBED * 2);
    unsigned short* Pb = A1;

    k_initcur<<<1, 256, 0, stream>>>(cursor, B);
    k_p1<<<(E + T1 - 1) / T1, 256, 0, stream>>>(ei, pairs, cursor, E, B);
    k_bscan<<<1, 256, 0, stream>>>(cursor, csrBase, rowptr, B, E, N);
    k_p2<<<B, GRP, 0, stream>>>(pairs, cursor, csrBase, csr, rowptr, dinv, N);

    k_gemm1<<<(N + 63) / 64, 256, 0, stream>>>(x, W1, dinv, A1, N);
    k_gf1<<<(N + 7) / 8, 256, 0, stream>>>(rowptr, csr, A1, dinv, b1, Hb, N);
    k_gf2h<<<(N + 7) / 8, 256, 0, stream>>>(rowptr, csr, Hb, dinv, Pb, N);
    k_fin<<<(N + 63) / 64, 256, 0, stream>>>(Pb, W2, b2, out, N);
}